// Round 7
// baseline (182.070 us; speedup 1.0000x reference)
//
#include <hip/hip_runtime.h>

// Sizes (fixed by the problem)
#define B_ 8192
#define T_ 256
#define I_ 28
#define H_ 10

// d_out layout: [B*T*H] output, then [2*B*H] h_final
#define OUT_MAIN (B_ * T_ * H_)   // 20971520
#define BH (B_ * H_)              // 81920

typedef __bf16 bf16x8 __attribute__((ext_vector_type(8)));
typedef float f32x16 __attribute__((ext_vector_type(16)));
union W4u { unsigned int w[4]; bf16x8 v; };

__device__ __forceinline__ float fast_tanh(float x) {
    // tanh(x) = 1 - 2/(exp(2x)+1); exp(2x) = exp2(x * 2*log2(e))
    float e = __builtin_amdgcn_exp2f(x * 2.885390081777927f);
    return __builtin_fmaf(-2.0f, __builtin_amdgcn_rcpf(e + 1.0f), 1.0f);
}

__device__ __forceinline__ unsigned short f2bf(float f) {  // f32 -> bf16 RNE
    unsigned u = __float_as_uint(f);
    unsigned r = ((u >> 16) & 1) + 0x7fff;
    return (unsigned short)((u + r) >> 16);
}

// ---------------- K1: xw0[b][t][u] = sum_i x[b][t][i] * Wih0[u][i] + (bih0[u]+bhh0[u])
// Memory-bound, ~roofline (~50 us, ~89% HBM). Unchanged from r2-r6.
__global__ __launch_bounds__(256) void rnn_k1(
        const float* __restrict__ x, const float* __restrict__ Wih0,
        const float* __restrict__ bih0, const float* __restrict__ bhh0,
        float* __restrict__ xw0) {
    __shared__ float Wl[H_ * I_];
    __shared__ float bl[H_];
    int tid = threadIdx.x;
    for (int i = tid; i < H_ * I_; i += 256) Wl[i] = Wih0[i];  // 280 > 256: loop!
    if (tid < H_) bl[tid] = bih0[tid] + bhh0[tid];
    __syncthreads();

    long row0 = ((long)blockIdx.x * 256 + tid) * 2;
    const float* xr = x + row0 * I_;
    float xa[I_], xb[I_];
#pragma unroll
    for (int i = 0; i < 7; i++) {
        float4 va = ((const float4*)xr)[i];
        float4 vb = ((const float4*)(xr + I_))[i];
        xa[4*i+0] = va.x; xa[4*i+1] = va.y; xa[4*i+2] = va.z; xa[4*i+3] = va.w;
        xb[4*i+0] = vb.x; xb[4*i+1] = vb.y; xb[4*i+2] = vb.z; xb[4*i+3] = vb.w;
    }
    float oa[H_], ob[H_];
#pragma unroll
    for (int u = 0; u < H_; u++) {
        float s0 = bl[u], s1 = bl[u];
#pragma unroll
        for (int i = 0; i < I_; i++) {
            float w = Wl[u * I_ + i];
            s0 = __builtin_fmaf(xa[i], w, s0);
            s1 = __builtin_fmaf(xb[i], w, s1);
        }
        oa[u] = s0; ob[u] = s1;
    }
    float* o = xw0 + row0 * H_;
#pragma unroll
    for (int i = 0; i < 5; i++) {
        ((float2*)o)[i]        = make_float2(oa[2*i], oa[2*i+1]);
        ((float2*)(o + H_))[i] = make_float2(ob[2*i], ob[2*i+1]);
    }
}

// ---------------- K2: MFMA recurrence (r6 post-mortem: DPP cross-lane ~6-8cyc
// effective -> any per-element ring is issue-bound; the matrix core does the
// cross-lane reduce for free).
// Per wave: 32 batches. v_mfma_f32_32x32x16_bf16: C[m=unit][n=batch],
// lane l: n=l&31, h=l>>5; C reg r -> m=(r&3)+8*(r>>2)+4h (regs 0..5 active).
// A (weights): lane holds A[m=l&31][k=8h+j]; B (h-vec): B[k=8h+j][n=l&31].
// C->B rebuild: 3 cvt_pk + 2 permlane32_swap (pads land exactly 0):
//   swap(t01,t45): t01 -> {t01_lo|t45_lo} = w0 ; t45 -> {t01_hi|t45_hi} = w2
//   swap(t23, 0 ): t23 -> {t23_lo|0}      = w1 ; 0   -> {t23_hi|0}      = w3
// xw0 streamed with an 8-deep statically-unrolled prefetch ring (in-flight
// bytes ~2.6MB across 256 waves -> ~6 TB/s); in-place overwrite trails reads
// by 8 steps. Only h,W are bf16; xw0/bias seed C in f32.
__global__ __launch_bounds__(64)
__attribute__((amdgpu_waves_per_eu(1, 1)))
void rnn_k2m(float* __restrict__ buf,            // d_out: xw0 in, output out
             const float* __restrict__ h0in,     // [2][B][H]
             const float* __restrict__ Whh0, const float* __restrict__ Wih1,
             const float* __restrict__ Whh1,
             const float* __restrict__ bih1, const float* __restrict__ bhh1,
             float* __restrict__ hfin) {         // d_out + OUT_MAIN
    const int l = threadIdx.x;
    const int n = l & 31;              // batch column (fixed through recurrence)
    const int h = l >> 5;              // K/M half
    const int bb = blockIdx.x * 32;
    const int am = n;                  // A-row index = l&31

    // ---- A fragments (weights, bf16, zero-padded), asm-pinned vs remat (r5)
    W4u a0u, aiu, ahu;
#pragma unroll
    for (int jj = 0; jj < 4; jj++) {
        int k0 = 8 * h + 2 * jj, k1 = k0 + 1;
        bool r0 = (am < H_) && (k0 < H_), r1 = (am < H_) && (k1 < H_);
        unsigned lo, hi;
        lo = r0 ? f2bf(Whh0[am * H_ + k0]) : 0u; hi = r1 ? f2bf(Whh0[am * H_ + k1]) : 0u;
        a0u.w[jj] = lo | (hi << 16);
        lo = r0 ? f2bf(Wih1[am * H_ + k0]) : 0u; hi = r1 ? f2bf(Wih1[am * H_ + k1]) : 0u;
        aiu.w[jj] = lo | (hi << 16);
        lo = r0 ? f2bf(Whh1[am * H_ + k0]) : 0u; hi = r1 ? f2bf(Whh1[am * H_ + k1]) : 0u;
        ahu.w[jj] = lo | (hi << 16);
    }
    bf16x8 A0 = a0u.v, Ai = aiu.v, Ah = ahu.v;
    asm volatile("" : "+v"(A0), "+v"(Ai), "+v"(Ah));

    // layer-1 bias per C-reg r=0..5 (m = (r&3)+8*(r>>2)+4h), pinned
    float bjr[6];
#pragma unroll
    for (int r = 0; r < 6; r++) {
        int mm = (r & 3) + 8 * (r >> 2) + 4 * h;
        bjr[r] = (mm < H_) ? (bih1[mm] + bhh1[mm]) : 0.f;
        asm volatile("" : "+v"(bjr[r]));
    }

    // ---- initial B fragments from h0 (zero-padded)
    W4u b0u, b1u;
#pragma unroll
    for (int jj = 0; jj < 4; jj++) {
        int k0 = 8 * h + 2 * jj, k1 = k0 + 1;
        float f0 = (k0 < H_) ? h0in[(bb + n) * H_ + k0] : 0.f;
        float f1 = (k1 < H_) ? h0in[(bb + n) * H_ + k1] : 0.f;
        b0u.w[jj] = (unsigned)f2bf(f0) | ((unsigned)f2bf(f1) << 16);
        f0 = (k0 < H_) ? h0in[BH + (bb + n) * H_ + k0] : 0.f;
        f1 = (k1 < H_) ? h0in[BH + (bb + n) * H_ + k1] : 0.f;
        b1u.w[jj] = (unsigned)f2bf(f0) | ((unsigned)f2bf(f1) << 16);
    }
    bf16x8 Bh0 = b0u.v, Bh1 = b1u.v;

    float* rowp = buf + (long)(bb + n) * (T_ * H_);
    const int xo = h ? 4 : 0;          // h=0 covers m0..3 (+m8,9); h=1 covers m4..7

    // ---- 8-deep xw0 prefetch ring (statically indexed via full unroll)
    float4 X4[8]; float2 X2[8];
#pragma unroll
    for (int s = 0; s < 8; s++) {
        X4[s] = *(const float4*)(rowp + s * H_ + xo);
        float2 q = *(const float2*)(rowp + s * H_ + 8);
        X2[s] = h ? make_float2(0.f, 0.f) : q;   // h=1: must be exact 0 (pad purity)
    }

    float v0,v1,v2,v3,v4,v5, g0,g1,g2,g3,g4,g5;

    for (int it = 0; it < T_ / 8; it++) {
        int tb = it * 8;
#pragma unroll
        for (int s = 0; s < 8; s++) {
            int t = tb + s;
            // ---- layer 0: C = Whh0·h0 + xw0  (C seed regs 6..15 are dont-care)
            f32x16 cs;
            cs[0]=X4[s].x; cs[1]=X4[s].y; cs[2]=X4[s].z; cs[3]=X4[s].w;
            cs[4]=X2[s].x; cs[5]=X2[s].y;
            f32x16 c0 = __builtin_amdgcn_mfma_f32_32x32x16_bf16(A0, Bh0, cs, 0, 0, 0);
            // prefetch slot t+8 (reads lead in-place writes by 8; clamp safe)
            int tp = (t + 8 < T_) ? t + 8 : T_ - 1;
            X4[s] = *(const float4*)(rowp + tp * H_ + xo);
            float2 q = *(const float2*)(rowp + tp * H_ + 8);
            X2[s] = h ? make_float2(0.f, 0.f) : q;
            v0 = fast_tanh(c0[0]); v1 = fast_tanh(c0[1]); v2 = fast_tanh(c0[2]);
            v3 = fast_tanh(c0[3]); v4 = fast_tanh(c0[4]); v5 = fast_tanh(c0[5]);
            // C -> B rebuild (h0_new)
            {
                unsigned t01, t23, t45, w3 = 0;
                asm("v_cvt_pk_bf16_f32 %0, %1, %2" : "=v"(t01) : "v"(v0), "v"(v1));
                asm("v_cvt_pk_bf16_f32 %0, %1, %2" : "=v"(t23) : "v"(v2), "v"(v3));
                asm("v_cvt_pk_bf16_f32 %0, %1, %2" : "=v"(t45) : "v"(v4), "v"(v5));
                asm volatile("s_nop 1" : "+v"(t01), "+v"(t23), "+v"(t45)); // VALU->permlane hazard
                asm("v_permlane32_swap_b32 %0, %1" : "+v"(t01), "+v"(t45));
                asm("v_permlane32_swap_b32 %0, %1" : "+v"(t23), "+v"(w3));
                W4u nb; nb.w[0] = t01; nb.w[1] = t23; nb.w[2] = t45; nb.w[3] = w3;
                Bh0 = nb.v;
            }
            // ---- layer 1: C = Wih1·h0_new + Whh1·h1_old + b1
            f32x16 cs1;
            cs1[0]=bjr[0]; cs1[1]=bjr[1]; cs1[2]=bjr[2];
            cs1[3]=bjr[3]; cs1[4]=bjr[4]; cs1[5]=bjr[5];
            f32x16 c1 = __builtin_amdgcn_mfma_f32_32x32x16_bf16(Ah, Bh1, cs1, 0, 0, 0);
            c1 = __builtin_amdgcn_mfma_f32_32x32x16_bf16(Ai, Bh0, c1, 0, 0, 0);
            g0 = fast_tanh(c1[0]); g1 = fast_tanh(c1[1]); g2 = fast_tanh(c1[2]);
            g3 = fast_tanh(c1[3]); g4 = fast_tanh(c1[4]); g5 = fast_tanh(c1[5]);
            // store output (overwrites consumed xw0 slot, 8 steps behind reads)
            float* op = rowp + t * H_;
            *(float4*)(op + xo) = make_float4(g0, g1, g2, g3);
            if (!h) *(float2*)(op + 8) = make_float2(g4, g5);
            // C -> B rebuild (h1_new)
            {
                unsigned u01, u23, u45, y3 = 0;
                asm("v_cvt_pk_bf16_f32 %0, %1, %2" : "=v"(u01) : "v"(g0), "v"(g1));
                asm("v_cvt_pk_bf16_f32 %0, %1, %2" : "=v"(u23) : "v"(g2), "v"(g3));
                asm("v_cvt_pk_bf16_f32 %0, %1, %2" : "=v"(u45) : "v"(g4), "v"(g5));
                asm volatile("s_nop 1" : "+v"(u01), "+v"(u23), "+v"(u45));
                asm("v_permlane32_swap_b32 %0, %1" : "+v"(u01), "+v"(u45));
                asm("v_permlane32_swap_b32 %0, %1" : "+v"(u23), "+v"(y3));
                W4u mb; mb.w[0] = u01; mb.w[1] = u23; mb.w[2] = u45; mb.w[3] = y3;
                Bh1 = mb.v;
            }
        }
    }
    // ---- h_final (last step's f32 values, same lane->element pattern)
    float* f0p = hfin + (long)(bb + n) * H_;
    *(float4*)(f0p + xo) = make_float4(v0, v1, v2, v3);
    if (!h) *(float2*)(f0p + 8) = make_float2(v4, v5);
    float* f1p = f0p + BH;
    *(float4*)(f1p + xo) = make_float4(g0, g1, g2, g3);
    if (!h) *(float2*)(f1p + 8) = make_float2(g4, g5);
}

extern "C" void kernel_launch(void* const* d_in, const int* in_sizes, int n_in,
                              void* d_out, int out_size, void* d_ws, size_t ws_size,
                              hipStream_t stream) {
    const float* x     = (const float*)d_in[0];
    const float* h0in  = (const float*)d_in[1];
    const float* Wih0  = (const float*)d_in[2];
    const float* Whh0  = (const float*)d_in[3];
    const float* bih0  = (const float*)d_in[4];
    const float* bhh0  = (const float*)d_in[5];
    const float* Wih1  = (const float*)d_in[6];
    const float* Whh1  = (const float*)d_in[7];
    const float* bih1  = (const float*)d_in[8];
    const float* bhh1  = (const float*)d_in[9];
    float* out = (float*)d_out;

    // K1: xw0 into d_out main region
    rnn_k1<<<dim3((B_ * T_) / 512), dim3(256), 0, stream>>>(x, Wih0, bih0, bhh0, out);
    // K2: 32 batches per wave -> 256 single-wave blocks (1 per CU)
    rnn_k2m<<<dim3(B_ / 32), dim3(64), 0, stream>>>(out, h0in, Whh0, Wih1, Whh1,
                                                    bih1, bhh1, out + OUT_MAIN);
}

// Round 8
// 135.682 us; speedup vs baseline: 1.3419x; 1.3419x over previous
//
#include <hip/hip_runtime.h>

// Sizes (fixed by the problem)
#define B_ 8192
#define T_ 256
#define I_ 28
#define H_ 10

// d_out layout: [B*T*H] output, then [2*B*H] h_final
#define OUT_MAIN (B_ * T_ * H_)   // 20971520
#define BH (B_ * H_)              // 81920

typedef __bf16 bf16x8 __attribute__((ext_vector_type(8)));
typedef float f32x16 __attribute__((ext_vector_type(16)));
union W4u { unsigned int w[4]; bf16x8 v; };

__device__ __forceinline__ float fast_tanh(float x) {
    // tanh(x) = 1 - 2/(exp(2x)+1); exp(2x) = exp2(x * 2*log2(e))
    float e = __builtin_amdgcn_exp2f(x * 2.885390081777927f);
    return __builtin_fmaf(-2.0f, __builtin_amdgcn_rcpf(e + 1.0f), 1.0f);
}

__device__ __forceinline__ unsigned short f2bf(float f) {  // f32 -> bf16 RNE
    unsigned u = __float_as_uint(f);
    unsigned r = ((u >> 16) & 1) + 0x7fff;
    return (unsigned short)((u + r) >> 16);
}

// pack (f0,f1) -> bf16 pair dh, and residual pair dl (split-bf16: f ~= hi + lo)
__device__ __forceinline__ void cvtpair(float f0, float f1, unsigned& dh, unsigned& dl) {
    asm("v_cvt_pk_bf16_f32 %0, %1, %2" : "=v"(dh) : "v"(f0), "v"(f1));
    float r0 = f0 - __uint_as_float(dh << 16);
    float r1 = f1 - __uint_as_float(dh & 0xffff0000u);
    asm("v_cvt_pk_bf16_f32 %0, %1, %2" : "=v"(dl) : "v"(r0), "v"(r1));
}

// C->B rebuild (validated r7): pads land exactly 0
#define REBUILD(vv0,vv1,vv2,vv3,vv4,vv5, DST) { \
    unsigned t01, t23, t45, w3 = 0; \
    asm("v_cvt_pk_bf16_f32 %0, %1, %2" : "=v"(t01) : "v"(vv0), "v"(vv1)); \
    asm("v_cvt_pk_bf16_f32 %0, %1, %2" : "=v"(t23) : "v"(vv2), "v"(vv3)); \
    asm("v_cvt_pk_bf16_f32 %0, %1, %2" : "=v"(t45) : "v"(vv4), "v"(vv5)); \
    asm volatile("s_nop 1" : "+v"(t01), "+v"(t23), "+v"(t45)); \
    asm("v_permlane32_swap_b32 %0, %1" : "+v"(t01), "+v"(t45)); \
    asm("v_permlane32_swap_b32 %0, %1" : "+v"(t23), "+v"(w3)); \
    W4u nb_; nb_.w[0]=t01; nb_.w[1]=t23; nb_.w[2]=t45; nb_.w[3]=w3; \
    DST = nb_.v; }

// x raw loads for step t into slot p. Per lane (h=l>>5):
//  fragA covers k=8h..8h+7  -> floats 8h..8h+7   (S0 @8h, S1 @8h+4)
//  fragB covers k=16+8h..+7 -> h=0: floats 16..23 (S2@16, S3@20); h=1: 24..27 (S2@24, S3=0)
#define LOADX(p, tt) { \
    const float* xp_ = xrow + (long)(tt) * I_; \
    S[p][0] = *(const float4*)(xp_ + 8*h); \
    S[p][1] = *(const float4*)(xp_ + 8*h + 4); \
    S[p][2] = *(const float4*)(xp_ + 16 + 8*h); \
    if (!h) S[p][3] = *(const float4*)(xp_ + 20); }

// build XC (layer-0 C tuple for one step) from slot p:
// XC = b0 + Wh*xl + Wl*xh + Wh*xh  (split-bf16 -> ~f32-accurate projection)
#define MAKEXC(p) { \
    W4u xhA, xlA, xhB, xlB; \
    cvtpair(S[p][0].x, S[p][0].y, xhA.w[0], xlA.w[0]); \
    cvtpair(S[p][0].z, S[p][0].w, xhA.w[1], xlA.w[1]); \
    cvtpair(S[p][1].x, S[p][1].y, xhA.w[2], xlA.w[2]); \
    cvtpair(S[p][1].z, S[p][1].w, xhA.w[3], xlA.w[3]); \
    cvtpair(S[p][2].x, S[p][2].y, xhB.w[0], xlB.w[0]); \
    cvtpair(S[p][2].z, S[p][2].w, xhB.w[1], xlB.w[1]); \
    cvtpair(S[p][3].x, S[p][3].y, xhB.w[2], xlB.w[2]); \
    cvtpair(S[p][3].z, S[p][3].w, xhB.w[3], xlB.w[3]); \
    f32x16 xc = __builtin_amdgcn_mfma_f32_32x32x16_bf16(Axh0, xlA.v, C0SEED, 0,0,0); \
    xc = __builtin_amdgcn_mfma_f32_32x32x16_bf16(Axh1, xlB.v, xc, 0,0,0); \
    xc = __builtin_amdgcn_mfma_f32_32x32x16_bf16(Axl0, xhA.v, xc, 0,0,0); \
    xc = __builtin_amdgcn_mfma_f32_32x32x16_bf16(Axl1, xhB.v, xc, 0,0,0); \
    xc = __builtin_amdgcn_mfma_f32_32x32x16_bf16(Axh0, xhA.v, xc, 0,0,0); \
    XC = __builtin_amdgcn_mfma_f32_32x32x16_bf16(Axh1, xhB.v, xc, 0,0,0); }

// Fully fused RNN: one kernel, K1 eliminated (r8). Per wave: 32 batches.
// v_mfma_f32_32x32x16_bf16 layouts validated r7:
//   C: lane l (n=l&31, h=l>>5), reg r -> m=(r&3)+8*(r>>2)+4h (regs 0..5 real)
//   A: lane holds A[m=l&31][k=8h+2jj(+1)]; B: lane holds B[k=8h+2jj(+1)][n=l&31]
// Phase A (critical): mfma(Ahh0,Bh0,XC) -> tanh -> rebuild -> mfma -> tanh -> rebuild
// Phase B (off-path): convert x_{t+1} (split hi/lo) + 6 MFMAs -> XC_{t+1};
//                     issue x-loads for t+4 (depth-4 static slot ring).
__global__ __launch_bounds__(64)
__attribute__((amdgpu_waves_per_eu(1, 1)))
void rnn_fused(const float* __restrict__ x, const float* __restrict__ h0in,
               const float* __restrict__ Wih0, const float* __restrict__ Whh0,
               const float* __restrict__ bih0, const float* __restrict__ bhh0,
               const float* __restrict__ Wih1, const float* __restrict__ Whh1,
               const float* __restrict__ bih1, const float* __restrict__ bhh1,
               float* __restrict__ out, float* __restrict__ hfin) {
    const int l = threadIdx.x;
    const int n = l & 31, h = l >> 5;
    const int bb = blockIdx.x * 32;
    const int am = n;

    // ---- recurrent A-frags (bf16, zero-padded), pinned vs remat (r5 lesson)
    W4u a0u, aiu, ahu;
#pragma unroll
    for (int jj = 0; jj < 4; jj++) {
        int k0 = 8*h + 2*jj, k1 = k0 + 1;
        bool r0 = (am < H_) && (k0 < H_), r1 = (am < H_) && (k1 < H_);
        unsigned lo, hi;
        lo = r0 ? f2bf(Whh0[am*H_+k0]) : 0u; hi = r1 ? f2bf(Whh0[am*H_+k1]) : 0u;
        a0u.w[jj] = lo | (hi<<16);
        lo = r0 ? f2bf(Wih1[am*H_+k0]) : 0u; hi = r1 ? f2bf(Wih1[am*H_+k1]) : 0u;
        aiu.w[jj] = lo | (hi<<16);
        lo = r0 ? f2bf(Whh1[am*H_+k0]) : 0u; hi = r1 ? f2bf(Whh1[am*H_+k1]) : 0u;
        ahu.w[jj] = lo | (hi<<16);
    }
    bf16x8 Ahh0 = a0u.v, Aih1 = aiu.v, Ahh1 = ahu.v;
    asm volatile("" : "+v"(Ahh0), "+v"(Aih1), "+v"(Ahh1));

    // ---- Wih0 split hi/lo A-frags, 2 K-slices (slice s: kg = 16s+8h+2jj)
    W4u xh0u, xh1u, xl0u, xl1u;
#pragma unroll
    for (int s = 0; s < 2; s++) {
#pragma unroll
        for (int jj = 0; jj < 4; jj++) {
            int k0 = 16*s + 8*h + 2*jj, k1 = k0 + 1;
            unsigned short h0b=0, h1b=0, l0b=0, l1b=0;
            if (am < H_ && k0 < I_) {
                float f = Wih0[am*I_+k0];
                h0b = f2bf(f);
                l0b = f2bf(f - __uint_as_float(((unsigned)h0b)<<16));
            }
            if (am < H_ && k1 < I_) {
                float f = Wih0[am*I_+k1];
                h1b = f2bf(f);
                l1b = f2bf(f - __uint_as_float(((unsigned)h1b)<<16));
            }
            unsigned wh = (unsigned)h0b | ((unsigned)h1b<<16);
            unsigned wl = (unsigned)l0b | ((unsigned)l1b<<16);
            if (s==0) { xh0u.w[jj]=wh; xl0u.w[jj]=wl; }
            else      { xh1u.w[jj]=wh; xl1u.w[jj]=wl; }
        }
    }
    bf16x8 Axh0 = xh0u.v, Axh1 = xh1u.v, Axl0 = xl0u.v, Axl1 = xl1u.v;
    asm volatile("" : "+v"(Axh0), "+v"(Axh1), "+v"(Axl0), "+v"(Axl1));

    // ---- persistent bias-seeded C tuples (no per-step seed movs), pinned
    f32x16 C0SEED, C1SEED;
#pragma unroll
    for (int r = 0; r < 16; r++) { C0SEED[r] = 0.f; C1SEED[r] = 0.f; }
#pragma unroll
    for (int r = 0; r < 6; r++) {
        int mm = (r & 3) + 8 * (r >> 2) + 4 * h;
        if (mm < H_) {
            C0SEED[r] = bih0[mm] + bhh0[mm];
            C1SEED[r] = bih1[mm] + bhh1[mm];
        }
    }
    asm volatile("" : "+v"(C0SEED), "+v"(C1SEED));

    // ---- initial B fragments from h0 (zero-padded)
    W4u b0u, b1u;
#pragma unroll
    for (int jj = 0; jj < 4; jj++) {
        int k0 = 8*h + 2*jj, k1 = k0 + 1;
        float f0 = (k0 < H_) ? h0in[(bb + n) * H_ + k0] : 0.f;
        float f1 = (k1 < H_) ? h0in[(bb + n) * H_ + k1] : 0.f;
        b0u.w[jj] = (unsigned)f2bf(f0) | ((unsigned)f2bf(f1) << 16);
        f0 = (k0 < H_) ? h0in[BH + (bb + n) * H_ + k0] : 0.f;
        f1 = (k1 < H_) ? h0in[BH + (bb + n) * H_ + k1] : 0.f;
        b1u.w[jj] = (unsigned)f2bf(f0) | ((unsigned)f2bf(f1) << 16);
    }
    bf16x8 Bh0 = b0u.v, Bh1 = b1u.v;

    const float* xrow = x   + (long)(bb + n) * (T_ * I_);
    float*       orow = out + (long)(bb + n) * (T_ * H_);
    const int xo = h ? 4 : 0;

    // ---- depth-4 x-load slot ring (static indices only)
    float4 S[4][4];
    float4 z4 = make_float4(0.f, 0.f, 0.f, 0.f);
    S[0][3] = z4; S[1][3] = z4; S[2][3] = z4; S[3][3] = z4;  // h=1 keeps 0 (k>=28 pad)
    LOADX(0, 0) LOADX(1, 1) LOADX(2, 2) LOADX(3, 3)

    f32x16 XC;
    MAKEXC(0)   // XC for t=0

    float v0,v1,v2,v3,v4,v5, g0,g1,g2,g3,g4,g5;

    for (int it = 0; it < T_ / 8; it++) {
#pragma unroll
        for (int s8 = 0; s8 < 8; s8++) {
            int t  = it * 8 + s8;
            int p  = t & 3;          // slot of x_t (dead: converted last step)
            int pn = (t + 1) & 3;    // slot of x_{t+1}
            // ---- phase A: recurrent critical path
            f32x16 c0 = __builtin_amdgcn_mfma_f32_32x32x16_bf16(Ahh0, Bh0, XC, 0,0,0);
            f32x16 c1 = __builtin_amdgcn_mfma_f32_32x32x16_bf16(Ahh1, Bh1, C1SEED, 0,0,0);
            v0 = fast_tanh(c0[0]); v1 = fast_tanh(c0[1]); v2 = fast_tanh(c0[2]);
            v3 = fast_tanh(c0[3]); v4 = fast_tanh(c0[4]); v5 = fast_tanh(c0[5]);
            REBUILD(v0,v1,v2,v3,v4,v5, Bh0)
            c1 = __builtin_amdgcn_mfma_f32_32x32x16_bf16(Aih1, Bh0, c1, 0,0,0);
            g0 = fast_tanh(c1[0]); g1 = fast_tanh(c1[1]); g2 = fast_tanh(c1[2]);
            g3 = fast_tanh(c1[3]); g4 = fast_tanh(c1[4]); g5 = fast_tanh(c1[5]);
            float* op = orow + t * H_;
            *(float4*)(op + xo) = make_float4(g0, g1, g2, g3);
            if (!h) *(float2*)(op + 8) = make_float2(g4, g5);
            REBUILD(g0,g1,g2,g3,g4,g5, Bh1)
            // ---- phase B: off-path x machinery
            MAKEXC(pn)                              // XC for t+1
            int tl = (t + 4 < T_) ? (t + 4) : (T_ - 1);
            LOADX(p, tl)                            // loads for t+4
        }
    }
    // ---- h_final
    float* f0p = hfin + (long)(bb + n) * H_;
    *(float4*)(f0p + xo) = make_float4(v0, v1, v2, v3);
    if (!h) *(float2*)(f0p + 8) = make_float2(v4, v5);
    float* f1p = f0p + BH;
    *(float4*)(f1p + xo) = make_float4(g0, g1, g2, g3);
    if (!h) *(float2*)(f1p + 8) = make_float2(g4, g5);
}

extern "C" void kernel_launch(void* const* d_in, const int* in_sizes, int n_in,
                              void* d_out, int out_size, void* d_ws, size_t ws_size,
                              hipStream_t stream) {
    const float* x     = (const float*)d_in[0];
    const float* h0in  = (const float*)d_in[1];
    const float* Wih0  = (const float*)d_in[2];
    const float* Whh0  = (const float*)d_in[3];
    const float* bih0  = (const float*)d_in[4];
    const float* bhh0  = (const float*)d_in[5];
    const float* Wih1  = (const float*)d_in[6];
    const float* Whh1  = (const float*)d_in[7];
    const float* bih1  = (const float*)d_in[8];
    const float* bhh1  = (const float*)d_in[9];
    float* out = (float*)d_out;

    // single fused kernel: 32 batches/wave -> 256 single-wave blocks
    rnn_fused<<<dim3(B_ / 32), dim3(64), 0, stream>>>(
        x, h0in, Wih0, Whh0, bih0, bhh0, Wih1, Whh1, bih1, bhh1,
        out, out + OUT_MAIN);
}